// Round 3
// baseline (2854.124 us; speedup 1.0000x reference)
//
#include <hip/hip_runtime.h>
#include <hip/hip_bf16.h>

typedef __hip_bfloat16 bf16;

// dual-mode float load: f32 ? float buffer : bf16 buffer (same element index)
static __device__ __forceinline__ float ldf(const void* p, long long i, bool f32) {
    return f32 ? ((const float*)p)[i] : __bfloat162float(((const bf16*)p)[i]);
}

// ---------------------------------------------------------------- encoding sniffer
// flags[0]: x is fp32?  flags[1]: weights are fp32?  flags[2]: edge_index is int64?
__global__ void sniff_kernel(const void* __restrict__ x, const void* __restrict__ w,
                             const int* __restrict__ ei, int E, int* __restrict__ flags) {
    __shared__ int cnt;
    if (threadIdx.x == 0) cnt = 0;
    __syncthreads();
    if (blockIdx.x < 2) {
        const unsigned short* u = (const unsigned short*)(blockIdx.x == 0 ? x : w);
        int bad = 0;
        for (int i = threadIdx.x; i < 4096; i += 256) {
            unsigned e = (u[i] >> 7) & 0xFF;
            if (e >= 0xA0) bad++;
        }
        atomicAdd(&cnt, bad);
        __syncthreads();
        if (threadIdx.x == 0) flags[blockIdx.x] = (cnt > 16) ? 1 : 0;
    } else {
        int nz = 0;
        for (int i = threadIdx.x; i < 1024; i += 256)
            if (ei[2 * i + 1] != 0) nz++;
        atomicAdd(&cnt, nz);
        __syncthreads();
        if (threadIdx.x == 0) flags[2] = (cnt == 0) ? 1 : 0;
    }
}

static __device__ __forceinline__ int ld_src(const int* ei, int E, int e, bool i64) {
    return i64 ? ei[2 * e] : ei[e];
}
static __device__ __forceinline__ int ld_dst(const int* ei, int E, int e, bool i64) {
    return i64 ? ei[2 * (E + e)] : ei[E + e];
}

// ---------------------------------------------------------------- degree counts (int)
__global__ void count_kernel(const int* __restrict__ ei, int E, const int* __restrict__ flags,
                             int* __restrict__ counts) {
    int i = blockIdx.x * blockDim.x + threadIdx.x;
    if (i >= E) return;
    bool i64 = flags[2] != 0;
    atomicAdd(&counts[ld_dst(ei, E, i, i64)], 1);
}

__global__ void dinv_kernel(const int* __restrict__ counts, float* __restrict__ dinv, int N) {
    int i = blockIdx.x * blockDim.x + threadIdx.x;
    if (i < N) dinv[i] = rsqrtf((float)counts[i] + 1.0f);
}

// ---------------------------------------------------------------- exclusive scan (single block)
__global__ void scan_kernel(const int* __restrict__ counts, int* __restrict__ rowptr, int N) {
    __shared__ int bs[256];
    const int T = 256;
    int chunk = (N + T - 1) / T;
    int lo = threadIdx.x * chunk;
    int hi = lo + chunk; if (hi > N) hi = N; if (lo > N) lo = N;
    int sum = 0;
    for (int i = lo; i < hi; i++) sum += counts[i];
    bs[threadIdx.x] = sum;
    __syncthreads();
    for (int off = 1; off < T; off <<= 1) {
        int t = 0;
        if ((int)threadIdx.x >= off) t = bs[threadIdx.x - off];
        __syncthreads();
        if ((int)threadIdx.x >= off) bs[threadIdx.x] += t;
        __syncthreads();
    }
    int run = bs[threadIdx.x] - sum;   // exclusive base for this thread's chunk
    for (int i = lo; i < hi; i++) { rowptr[i] = run; run += counts[i]; }
    if (hi == N && lo < N) rowptr[N] = run;
    if (N == 0 && threadIdx.x == 0) rowptr[0] = 0;
}

// ---------------------------------------------------------------- CSR fill (counting sort by dst)
__global__ void fill_kernel(const int* __restrict__ ei, int E, const int* __restrict__ flags,
                            const int* __restrict__ rowptr, int* __restrict__ cursor,
                            int* __restrict__ csr_src) {
    int e = blockIdx.x * blockDim.x + threadIdx.x;
    if (e >= E) return;
    bool i64 = flags[2] != 0;
    int s = ld_src(ei, E, e, i64), d = ld_dst(ei, E, e, i64);
    int p = atomicAdd(&cursor[d], 1);
    csr_src[rowptr[d] + p] = s;
}

// ---------------------------------------------------------------- GEMM1: x[N,128] @ W1[128,64] -> h1x[N,64]
// block 256 = 64 cols x 4 row-groups; each thread 4 consecutive rows (16 rows/block)
__global__ void gemm1_kernel(const void* __restrict__ x, const void* __restrict__ W1,
                             const int* __restrict__ flags, float* __restrict__ h1x, int N) {
    __shared__ float Ws[128 * 64];  // 32 KB
    __shared__ float Xs[16 * 128];  // 8 KB
    bool fx = flags[0] != 0, fw = flags[1] != 0;
    for (int i = threadIdx.x; i < 128 * 64; i += 256) Ws[i] = ldf(W1, i, fw);
    int base = blockIdx.x * 16;
    for (int i = threadIdx.x; i < 16 * 128; i += 256) {
        int r = i >> 7, k = i & 127;
        int n = base + r;
        Xs[i] = (n < N) ? ldf(x, (long long)n * 128 + k, fx) : 0.f;
    }
    __syncthreads();
    int c = threadIdx.x & 63, rg = threadIdx.x >> 6;
    const float* x0 = &Xs[(rg * 4 + 0) * 128];
    const float* x1 = &Xs[(rg * 4 + 1) * 128];
    const float* x2 = &Xs[(rg * 4 + 2) * 128];
    const float* x3 = &Xs[(rg * 4 + 3) * 128];
    float a0 = 0.f, a1 = 0.f, a2 = 0.f, a3 = 0.f;
    for (int k = 0; k < 128; k += 4) {
        float4 v0 = *(const float4*)&x0[k];
        float4 v1 = *(const float4*)&x1[k];
        float4 v2 = *(const float4*)&x2[k];
        float4 v3 = *(const float4*)&x3[k];
        float w0 = Ws[(k + 0) * 64 + c], w1 = Ws[(k + 1) * 64 + c];
        float w2 = Ws[(k + 2) * 64 + c], w3 = Ws[(k + 3) * 64 + c];
        a0 = fmaf(v0.x, w0, fmaf(v0.y, w1, fmaf(v0.z, w2, fmaf(v0.w, w3, a0))));
        a1 = fmaf(v1.x, w0, fmaf(v1.y, w1, fmaf(v1.z, w2, fmaf(v1.w, w3, a1))));
        a2 = fmaf(v2.x, w0, fmaf(v2.y, w1, fmaf(v2.z, w2, fmaf(v2.w, w3, a2))));
        a3 = fmaf(v3.x, w0, fmaf(v3.y, w1, fmaf(v3.z, w2, fmaf(v3.w, w3, a3))));
    }
    int n0 = base + rg * 4;
    if (n0 + 0 < N) h1x[(long long)(n0 + 0) * 64 + c] = a0;
    if (n0 + 1 < N) h1x[(long long)(n0 + 1) * 64 + c] = a1;
    if (n0 + 2 < N) h1x[(long long)(n0 + 2) * 64 + c] = a2;
    if (n0 + 3 < N) h1x[(long long)(n0 + 3) * 64 + c] = a3;
}

// ---------------------------------------------------------------- gather layer 1: one wave per node, lane=channel
// h1 = relu(sum_{e in CSR[n]} h1x[src]*dinv[src]*dinv[n] + h1x[n]*dinv[n]^2 + b1)
__global__ void gather1_kernel(const float* __restrict__ h1x, const float* __restrict__ dinv,
                               const int* __restrict__ rowptr, const int* __restrict__ csr_src,
                               const void* __restrict__ b1, const int* __restrict__ flags,
                               float* __restrict__ h1, int N) {
    bool fw = flags[1] != 0;
    int lane = threadIdx.x & 63;
    int node = blockIdx.x * 4 + (threadIdx.x >> 6);
    if (node >= N) return;
    int beg = rowptr[node], end = rowptr[node + 1];
    float dvd = dinv[node];
    float acc = 0.f;
    for (int b = beg; b < end; b += 64) {
        int cnt = end - b; if (cnt > 64) cnt = 64;
        int s = 0; float dvs = 0.f;
        if (lane < cnt) { s = csr_src[b + lane]; dvs = dinv[s]; }
        for (int j = 0; j < cnt; j++) {
            int sj = __shfl(s, j);
            float nm = __shfl(dvs, j) * dvd;
            acc = fmaf(h1x[(long long)sj * 64 + lane], nm, acc);
        }
    }
    float v = acc + h1x[(long long)node * 64 + lane] * (dvd * dvd) + ldf(b1, lane, fw);
    h1[(long long)node * 64 + lane] = fmaxf(v, 0.f);
}

// ---------------------------------------------------------------- GEMM2: h1[N,64] @ W2[64,32] -> h2x[N,32]
// block 256 = 32 cols x 8 row-groups; each thread 4 consecutive rows (32 rows/block)
__global__ void gemm2_kernel(const float* __restrict__ h1, const void* __restrict__ W2,
                             const int* __restrict__ flags, float* __restrict__ h2x, int N) {
    __shared__ float Ws[64 * 32];  // 8 KB
    __shared__ float Xs[32 * 64];  // 8 KB
    bool fw = flags[1] != 0;
    for (int i = threadIdx.x; i < 64 * 32; i += 256) Ws[i] = ldf(W2, i, fw);
    int base = blockIdx.x * 32;
    for (int i = threadIdx.x; i < 32 * 64; i += 256) {
        int r = i >> 6, k = i & 63;
        int n = base + r;
        Xs[i] = (n < N) ? h1[(long long)n * 64 + k] : 0.f;
    }
    __syncthreads();
    int c = threadIdx.x & 31, rg = threadIdx.x >> 5;
    const float* x0 = &Xs[(rg * 4 + 0) * 64];
    const float* x1 = &Xs[(rg * 4 + 1) * 64];
    const float* x2 = &Xs[(rg * 4 + 2) * 64];
    const float* x3 = &Xs[(rg * 4 + 3) * 64];
    float a0 = 0.f, a1 = 0.f, a2 = 0.f, a3 = 0.f;
    for (int k = 0; k < 64; k += 4) {
        float4 v0 = *(const float4*)&x0[k];
        float4 v1 = *(const float4*)&x1[k];
        float4 v2 = *(const float4*)&x2[k];
        float4 v3 = *(const float4*)&x3[k];
        float w0 = Ws[(k + 0) * 32 + c], w1 = Ws[(k + 1) * 32 + c];
        float w2 = Ws[(k + 2) * 32 + c], w3 = Ws[(k + 3) * 32 + c];
        a0 = fmaf(v0.x, w0, fmaf(v0.y, w1, fmaf(v0.z, w2, fmaf(v0.w, w3, a0))));
        a1 = fmaf(v1.x, w0, fmaf(v1.y, w1, fmaf(v1.z, w2, fmaf(v1.w, w3, a1))));
        a2 = fmaf(v2.x, w0, fmaf(v2.y, w1, fmaf(v2.z, w2, fmaf(v2.w, w3, a2))));
        a3 = fmaf(v3.x, w0, fmaf(v3.y, w1, fmaf(v3.z, w2, fmaf(v3.w, w3, a3))));
    }
    int n0 = base + rg * 4;
    if (n0 + 0 < N) h2x[(long long)(n0 + 0) * 32 + c] = a0;
    if (n0 + 1 < N) h2x[(long long)(n0 + 1) * 32 + c] = a1;
    if (n0 + 2 < N) h2x[(long long)(n0 + 2) * 32 + c] = a2;
    if (n0 + 3 < N) h2x[(long long)(n0 + 3) * 32 + c] = a3;
}

// ---------------------------------------------------------------- final: fused gather2 + cat@Wl + log_softmax
// block 256 = 8 nodes x 32 outputs; Wl in LDS (28KB), cat rows in LDS (7KB)
__global__ void final_kernel(const void* __restrict__ x, const float* __restrict__ h1,
                             const float* __restrict__ h2x, const float* __restrict__ dinv,
                             const int* __restrict__ rowptr, const int* __restrict__ csr_src,
                             const void* __restrict__ b2, const void* __restrict__ Wl,
                             const void* __restrict__ bl, const int* __restrict__ flags,
                             void* __restrict__ out, int N) {
    __shared__ float Ws[224 * 32];
    __shared__ float Cs[8 * 224];
    bool fx = flags[0] != 0, fw = flags[1] != 0;
    for (int i = threadIdx.x; i < 224 * 32; i += 256) Ws[i] = ldf(Wl, i, fw);
    int base = blockIdx.x * 8;
    // stage x (128) and h1 (64) parts of cat
    for (int i = threadIdx.x; i < 8 * 192; i += 256) {
        int r = i / 192, k = i % 192;
        int n = base + r;
        float v = 0.f;
        if (n < N) v = (k < 128) ? ldf(x, (long long)n * 128 + k, fx)
                                 : h1[(long long)n * 64 + (k - 128)];
        Cs[r * 224 + k] = v;
    }
    // fused gather for h2 part: 32 lanes per node
    int g = threadIdx.x >> 5, j = threadIdx.x & 31;
    int n = base + g;
    if (n < N) {
        float dvd = dinv[n];
        int beg = rowptr[n], end = rowptr[n + 1];
        float acc = 0.f;
        for (int b = beg; b < end; b += 32) {
            int cnt = end - b; if (cnt > 32) cnt = 32;
            int s = 0; float dvs = 0.f;
            if (j < cnt) { s = csr_src[b + j]; dvs = dinv[s]; }
            for (int jj = 0; jj < cnt; jj++) {
                int sj = __shfl(s, jj, 32);
                float nm = __shfl(dvs, jj, 32) * dvd;
                acc = fmaf(h2x[(long long)sj * 32 + j], nm, acc);
            }
        }
        acc += h2x[(long long)n * 32 + j] * (dvd * dvd) + ldf(b2, j, fw);
        Cs[g * 224 + 192 + j] = acc;
    }
    __syncthreads();
    float acc = ldf(bl, j, fw);
    const float* cr = &Cs[g * 224];
    for (int k = 0; k < 224; k += 4) {
        float4 cv = *(const float4*)&cr[k];
        acc = fmaf(cv.x, Ws[(k + 0) * 32 + j],
              fmaf(cv.y, Ws[(k + 1) * 32 + j],
              fmaf(cv.z, Ws[(k + 2) * 32 + j],
              fmaf(cv.w, Ws[(k + 3) * 32 + j], acc))));
    }
    float m = acc;
    for (int o = 16; o > 0; o >>= 1) m = fmaxf(m, __shfl_xor(m, o, 32));
    float ex = __expf(acc - m);
    float s = ex;
    for (int o = 16; o > 0; o >>= 1) s += __shfl_xor(s, o, 32);
    float r = acc - m - __logf(s);
    if (n < N) {
        if (fx) ((float*)out)[(long long)n * 32 + j] = r;
        else    ((bf16*)out)[(long long)n * 32 + j] = __float2bfloat16(r);
    }
}

extern "C" void kernel_launch(void* const* d_in, const int* in_sizes, int n_in,
                              void* d_out, int out_size, void* d_ws, size_t ws_size,
                              hipStream_t stream) {
    const void* x  = d_in[0];
    const int*  ei = (const int*)d_in[1];
    const void* W1 = d_in[2];
    const void* b1 = d_in[3];
    const void* W2 = d_in[4];
    const void* b2 = d_in[5];
    const void* Wl = d_in[6];
    const void* bl = d_in[7];

    int N = in_sizes[0] / 128;
    int E = in_sizes[1] / 2;

    // ws layout (4B units): [flags 16 | counts N | cursor N | dinv N | rowptr N+16 | csr_src E | h1x N*64 | h1 N*64]
    // h2x aliases h1x (dead after gather1). ~59 MB total.
    int* ip      = (int*)d_ws;
    int* flags   = ip;
    int* counts  = ip + 16;
    int* cursor  = counts + N;
    float* dinv  = (float*)(cursor + N);
    int* rowptr  = (int*)(dinv + N);
    int* csr_src = rowptr + N + 16;
    float* h1x   = (float*)(csr_src + E);
    float* h1    = h1x + (size_t)N * 64;
    float* h2x   = h1x;  // alias

    // zero flags + counts + cursor (contiguous)
    hipMemsetAsync(ip, 0, (size_t)(16 + 2 * N) * sizeof(int), stream);

    sniff_kernel<<<3, 256, 0, stream>>>(x, W1, ei, E, flags);
    count_kernel<<<(E + 255) / 256, 256, 0, stream>>>(ei, E, flags, counts);
    dinv_kernel<<<(N + 255) / 256, 256, 0, stream>>>(counts, dinv, N);
    scan_kernel<<<1, 256, 0, stream>>>(counts, rowptr, N);
    fill_kernel<<<(E + 255) / 256, 256, 0, stream>>>(ei, E, flags, rowptr, cursor, csr_src);

    gemm1_kernel<<<(N + 15) / 16, 256, 0, stream>>>(x, W1, flags, h1x, N);
    gather1_kernel<<<(N + 3) / 4, 256, 0, stream>>>(h1x, dinv, rowptr, csr_src, b1, flags, h1, N);
    gemm2_kernel<<<(N + 31) / 32, 256, 0, stream>>>(h1, W2, flags, h2x, N);
    final_kernel<<<(N + 7) / 8, 256, 0, stream>>>(x, h1, h2x, dinv, rowptr, csr_src, b2, Wl, bl, flags, d_out, N);
}

// Round 4
// 2328.262 us; speedup vs baseline: 1.2259x; 1.2259x over previous
//
#include <hip/hip_runtime.h>
#include <hip/hip_bf16.h>

typedef __hip_bfloat16 bf16;

// dual-mode float load: f32 ? float buffer : bf16 buffer (same element index)
static __device__ __forceinline__ float ldf(const void* p, long long i, bool f32) {
    return f32 ? ((const float*)p)[i] : __bfloat162float(((const bf16*)p)[i]);
}

// ---------------------------------------------------------------- encoding sniffer
// flags[0]: x is fp32?  flags[1]: weights are fp32?  flags[2]: edge_index is int64?
__global__ __launch_bounds__(256, 4)
void sniff_kernel(const void* __restrict__ x, const void* __restrict__ w,
                  const int* __restrict__ ei, int E, int* __restrict__ flags) {
    __shared__ int cnt;
    if (threadIdx.x == 0) cnt = 0;
    __syncthreads();
    if (blockIdx.x < 2) {
        const unsigned short* u = (const unsigned short*)(blockIdx.x == 0 ? x : w);
        int bad = 0;
        for (int i = threadIdx.x; i < 4096; i += 256) {
            unsigned e = (u[i] >> 7) & 0xFF;
            if (e >= 0xA0) bad++;
        }
        atomicAdd(&cnt, bad);
        __syncthreads();
        if (threadIdx.x == 0) flags[blockIdx.x] = (cnt > 16) ? 1 : 0;
    } else {
        int nz = 0;
        for (int i = threadIdx.x; i < 1024; i += 256)
            if (ei[2 * i + 1] != 0) nz++;
        atomicAdd(&cnt, nz);
        __syncthreads();
        if (threadIdx.x == 0) flags[2] = (cnt == 0) ? 1 : 0;
    }
}

static __device__ __forceinline__ int ld_src(const int* ei, int E, int e, bool i64) {
    return i64 ? ei[2 * e] : ei[e];
}
static __device__ __forceinline__ int ld_dst(const int* ei, int E, int e, bool i64) {
    return i64 ? ei[2 * (E + e)] : ei[E + e];
}

// ---------------------------------------------------------------- degree counts (int)
__global__ __launch_bounds__(256, 4)
void count_kernel(const int* __restrict__ ei, int E, const int* __restrict__ flags,
                  int* __restrict__ counts) {
    int i = blockIdx.x * blockDim.x + threadIdx.x;
    if (i >= E) return;
    bool i64 = flags[2] != 0;
    atomicAdd(&counts[ld_dst(ei, E, i, i64)], 1);
}

__global__ __launch_bounds__(256, 4)
void dinv_kernel(const int* __restrict__ counts, float* __restrict__ dinv, int N) {
    int i = blockIdx.x * blockDim.x + threadIdx.x;
    if (i < N) dinv[i] = rsqrtf((float)counts[i] + 1.0f);
}

// ---------------------------------------------------------------- exclusive scan (single block)
__global__ __launch_bounds__(256, 4)
void scan_kernel(const int* __restrict__ counts, int* __restrict__ rowptr, int N) {
    __shared__ int bs[256];
    const int T = 256;
    int chunk = (N + T - 1) / T;
    int lo = threadIdx.x * chunk;
    int hi = lo + chunk; if (hi > N) hi = N; if (lo > N) lo = N;
    int sum = 0;
    for (int i = lo; i < hi; i++) sum += counts[i];
    bs[threadIdx.x] = sum;
    __syncthreads();
    for (int off = 1; off < T; off <<= 1) {
        int t = 0;
        if ((int)threadIdx.x >= off) t = bs[threadIdx.x - off];
        __syncthreads();
        if ((int)threadIdx.x >= off) bs[threadIdx.x] += t;
        __syncthreads();
    }
    int run = bs[threadIdx.x] - sum;   // exclusive base for this thread's chunk
    for (int i = lo; i < hi; i++) { rowptr[i] = run; run += counts[i]; }
    if (hi == N && lo < N) rowptr[N] = run;
    if (N == 0 && threadIdx.x == 0) rowptr[0] = 0;
}

// ---------------------------------------------------------------- CSR fill (counting sort by dst)
__global__ __launch_bounds__(256, 4)
void fill_kernel(const int* __restrict__ ei, int E, const int* __restrict__ flags,
                 const int* __restrict__ rowptr, int* __restrict__ cursor,
                 int* __restrict__ csr_src) {
    int e = blockIdx.x * blockDim.x + threadIdx.x;
    if (e >= E) return;
    bool i64 = flags[2] != 0;
    int s = ld_src(ei, E, e, i64), d = ld_dst(ei, E, e, i64);
    int p = atomicAdd(&cursor[d], 1);
    csr_src[rowptr[d] + p] = s;
}

// ---------------------------------------------------------------- GEMM1: x[N,128] @ W1[128,64] -> h1x[N,64]
// block 256 = 64 cols x 4 row-groups; each thread 4 consecutive rows (16 rows/block)
// __launch_bounds__(256,2): lift the default VGPR cap (64) that caused scratch spills in R3
__global__ __launch_bounds__(256, 2)
void gemm1_kernel(const void* __restrict__ x, const void* __restrict__ W1,
                  const int* __restrict__ flags, float* __restrict__ h1x, int N) {
    __shared__ float Ws[128 * 64];  // 32 KB
    __shared__ float Xs[16 * 128];  // 8 KB
    bool fx = flags[0] != 0, fw = flags[1] != 0;
    for (int i = threadIdx.x; i < 128 * 64; i += 256) Ws[i] = ldf(W1, i, fw);
    int base = blockIdx.x * 16;
    for (int i = threadIdx.x; i < 16 * 128; i += 256) {
        int r = i >> 7, k = i & 127;
        int n = base + r;
        Xs[i] = (n < N) ? ldf(x, (long long)n * 128 + k, fx) : 0.f;
    }
    __syncthreads();
    int c = threadIdx.x & 63, rg = threadIdx.x >> 6;
    const float* x0 = &Xs[(rg * 4 + 0) * 128];
    const float* x1 = &Xs[(rg * 4 + 1) * 128];
    const float* x2 = &Xs[(rg * 4 + 2) * 128];
    const float* x3 = &Xs[(rg * 4 + 3) * 128];
    float a0 = 0.f, a1 = 0.f, a2 = 0.f, a3 = 0.f;
    for (int k = 0; k < 128; k += 4) {
        float4 v0 = *(const float4*)&x0[k];
        float4 v1 = *(const float4*)&x1[k];
        float4 v2 = *(const float4*)&x2[k];
        float4 v3 = *(const float4*)&x3[k];
        float w0 = Ws[(k + 0) * 64 + c], w1 = Ws[(k + 1) * 64 + c];
        float w2 = Ws[(k + 2) * 64 + c], w3 = Ws[(k + 3) * 64 + c];
        a0 = fmaf(v0.x, w0, fmaf(v0.y, w1, fmaf(v0.z, w2, fmaf(v0.w, w3, a0))));
        a1 = fmaf(v1.x, w0, fmaf(v1.y, w1, fmaf(v1.z, w2, fmaf(v1.w, w3, a1))));
        a2 = fmaf(v2.x, w0, fmaf(v2.y, w1, fmaf(v2.z, w2, fmaf(v2.w, w3, a2))));
        a3 = fmaf(v3.x, w0, fmaf(v3.y, w1, fmaf(v3.z, w2, fmaf(v3.w, w3, a3))));
    }
    int n0 = base + rg * 4;
    if (n0 + 0 < N) h1x[(long long)(n0 + 0) * 64 + c] = a0;
    if (n0 + 1 < N) h1x[(long long)(n0 + 1) * 64 + c] = a1;
    if (n0 + 2 < N) h1x[(long long)(n0 + 2) * 64 + c] = a2;
    if (n0 + 3 < N) h1x[(long long)(n0 + 3) * 64 + c] = a3;
}

// ---------------------------------------------------------------- gather layer 1: one wave per node, lane=channel
__global__ __launch_bounds__(256, 4)
void gather1_kernel(const float* __restrict__ h1x, const float* __restrict__ dinv,
                    const int* __restrict__ rowptr, const int* __restrict__ csr_src,
                    const void* __restrict__ b1, const int* __restrict__ flags,
                    float* __restrict__ h1, int N) {
    bool fw = flags[1] != 0;
    int lane = threadIdx.x & 63;
    int node = blockIdx.x * 4 + (threadIdx.x >> 6);
    if (node >= N) return;
    int beg = rowptr[node], end = rowptr[node + 1];
    float dvd = dinv[node];
    float acc = 0.f;
    for (int b = beg; b < end; b += 64) {
        int cnt = end - b; if (cnt > 64) cnt = 64;
        int s = 0; float dvs = 0.f;
        if (lane < cnt) { s = csr_src[b + lane]; dvs = dinv[s]; }
        for (int j = 0; j < cnt; j++) {
            int sj = __shfl(s, j);
            float nm = __shfl(dvs, j) * dvd;
            acc = fmaf(h1x[(long long)sj * 64 + lane], nm, acc);
        }
    }
    float v = acc + h1x[(long long)node * 64 + lane] * (dvd * dvd) + ldf(b1, lane, fw);
    h1[(long long)node * 64 + lane] = fmaxf(v, 0.f);
}

// ---------------------------------------------------------------- GEMM2: h1[N,64] @ W2[64,32] -> h2x[N,32]
__global__ __launch_bounds__(256, 2)
void gemm2_kernel(const float* __restrict__ h1, const void* __restrict__ W2,
                  const int* __restrict__ flags, float* __restrict__ h2x, int N) {
    __shared__ float Ws[64 * 32];  // 8 KB
    __shared__ float Xs[32 * 64];  // 8 KB
    bool fw = flags[1] != 0;
    for (int i = threadIdx.x; i < 64 * 32; i += 256) Ws[i] = ldf(W2, i, fw);
    int base = blockIdx.x * 32;
    for (int i = threadIdx.x; i < 32 * 64; i += 256) {
        int r = i >> 6, k = i & 63;
        int n = base + r;
        Xs[i] = (n < N) ? h1[(long long)n * 64 + k] : 0.f;
    }
    __syncthreads();
    int c = threadIdx.x & 31, rg = threadIdx.x >> 5;
    const float* x0 = &Xs[(rg * 4 + 0) * 64];
    const float* x1 = &Xs[(rg * 4 + 1) * 64];
    const float* x2 = &Xs[(rg * 4 + 2) * 64];
    const float* x3 = &Xs[(rg * 4 + 3) * 64];
    float a0 = 0.f, a1 = 0.f, a2 = 0.f, a3 = 0.f;
    for (int k = 0; k < 64; k += 4) {
        float4 v0 = *(const float4*)&x0[k];
        float4 v1 = *(const float4*)&x1[k];
        float4 v2 = *(const float4*)&x2[k];
        float4 v3 = *(const float4*)&x3[k];
        float w0 = Ws[(k + 0) * 32 + c], w1 = Ws[(k + 1) * 32 + c];
        float w2 = Ws[(k + 2) * 32 + c], w3 = Ws[(k + 3) * 32 + c];
        a0 = fmaf(v0.x, w0, fmaf(v0.y, w1, fmaf(v0.z, w2, fmaf(v0.w, w3, a0))));
        a1 = fmaf(v1.x, w0, fmaf(v1.y, w1, fmaf(v1.z, w2, fmaf(v1.w, w3, a1))));
        a2 = fmaf(v2.x, w0, fmaf(v2.y, w1, fmaf(v2.z, w2, fmaf(v2.w, w3, a2))));
        a3 = fmaf(v3.x, w0, fmaf(v3.y, w1, fmaf(v3.z, w2, fmaf(v3.w, w3, a3))));
    }
    int n0 = base + rg * 4;
    if (n0 + 0 < N) h2x[(long long)(n0 + 0) * 32 + c] = a0;
    if (n0 + 1 < N) h2x[(long long)(n0 + 1) * 32 + c] = a1;
    if (n0 + 2 < N) h2x[(long long)(n0 + 2) * 32 + c] = a2;
    if (n0 + 3 < N) h2x[(long long)(n0 + 3) * 32 + c] = a3;
}

// ---------------------------------------------------------------- final: fused gather2 + cat@Wl + log_softmax
__global__ __launch_bounds__(256, 2)
void final_kernel(const void* __restrict__ x, const float* __restrict__ h1,
                  const float* __restrict__ h2x, const float* __restrict__ dinv,
                  const int* __restrict__ rowptr, const int* __restrict__ csr_src,
                  const void* __restrict__ b2, const void* __restrict__ Wl,
                  const void* __restrict__ bl, const int* __restrict__ flags,
                  void* __restrict__ out, int N) {
    __shared__ float Ws[224 * 32];
    __shared__ float Cs[8 * 224];
    bool fx = flags[0] != 0, fw = flags[1] != 0;
    for (int i = threadIdx.x; i < 224 * 32; i += 256) Ws[i] = ldf(Wl, i, fw);
    int base = blockIdx.x * 8;
    for (int i = threadIdx.x; i < 8 * 192; i += 256) {
        int r = i / 192, k = i % 192;
        int n = base + r;
        float v = 0.f;
        if (n < N) v = (k < 128) ? ldf(x, (long long)n * 128 + k, fx)
                                 : h1[(long long)n * 64 + (k - 128)];
        Cs[r * 224 + k] = v;
    }
    int g = threadIdx.x >> 5, j = threadIdx.x & 31;
    int n = base + g;
    if (n < N) {
        float dvd = dinv[n];
        int beg = rowptr[n], end = rowptr[n + 1];
        float acc = 0.f;
        for (int b = beg; b < end; b += 32) {
            int cnt = end - b; if (cnt > 32) cnt = 32;
            int s = 0; float dvs = 0.f;
            if (j < cnt) { s = csr_src[b + j]; dvs = dinv[s]; }
            for (int jj = 0; jj < cnt; jj++) {
                int sj = __shfl(s, jj, 32);
                float nm = __shfl(dvs, jj, 32) * dvd;
                acc = fmaf(h2x[(long long)sj * 32 + j], nm, acc);
            }
        }
        acc += h2x[(long long)n * 32 + j] * (dvd * dvd) + ldf(b2, j, fw);
        Cs[g * 224 + 192 + j] = acc;
    }
    __syncthreads();
    float acc = ldf(bl, j, fw);
    const float* cr = &Cs[g * 224];
    for (int k = 0; k < 224; k += 4) {
        float4 cv = *(const float4*)&cr[k];
        acc = fmaf(cv.x, Ws[(k + 0) * 32 + j],
              fmaf(cv.y, Ws[(k + 1) * 32 + j],
              fmaf(cv.z, Ws[(k + 2) * 32 + j],
              fmaf(cv.w, Ws[(k + 3) * 32 + j], acc))));
    }
    float m = acc;
    for (int o = 16; o > 0; o >>= 1) m = fmaxf(m, __shfl_xor(m, o, 32));
    float ex = __expf(acc - m);
    float s = ex;
    for (int o = 16; o > 0; o >>= 1) s += __shfl_xor(s, o, 32);
    float r = acc - m - __logf(s);
    if (n < N) {
        if (fx) ((float*)out)[(long long)n * 32 + j] = r;
        else    ((bf16*)out)[(long long)n * 32 + j] = __float2bfloat16(r);
    }
}

extern "C" void kernel_launch(void* const* d_in, const int* in_sizes, int n_in,
                              void* d_out, int out_size, void* d_ws, size_t ws_size,
                              hipStream_t stream) {
    const void* x  = d_in[0];
    const int*  ei = (const int*)d_in[1];
    const void* W1 = d_in[2];
    const void* b1 = d_in[3];
    const void* W2 = d_in[4];
    const void* b2 = d_in[5];
    const void* Wl = d_in[6];
    const void* bl = d_in[7];

    int N = in_sizes[0] / 128;
    int E = in_sizes[1] / 2;

    // ws layout (4B units): [flags 16 | counts N | cursor N | dinv N | rowptr N+16 | csr_src E | h1x N*64 | h1 N*64]
    int* ip      = (int*)d_ws;
    int* flags   = ip;
    int* counts  = ip + 16;
    int* cursor  = counts + N;
    float* dinv  = (float*)(cursor + N);
    int* rowptr  = (int*)(dinv + N);
    int* csr_src = rowptr + N + 16;
    float* h1x   = (float*)(csr_src + E);
    float* h1    = h1x + (size_t)N * 64;
    float* h2x   = h1x;  // alias (h1x dead after gather1)

    hipMemsetAsync(ip, 0, (size_t)(16 + 2 * N) * sizeof(int), stream);

    sniff_kernel<<<3, 256, 0, stream>>>(x, W1, ei, E, flags);
    count_kernel<<<(E + 255) / 256, 256, 0, stream>>>(ei, E, flags, counts);
    dinv_kernel<<<(N + 255) / 256, 256, 0, stream>>>(counts, dinv, N);
    scan_kernel<<<1, 256, 0, stream>>>(counts, rowptr, N);
    fill_kernel<<<(E + 255) / 256, 256, 0, stream>>>(ei, E, flags, rowptr, cursor, csr_src);

    gemm1_kernel<<<(N + 15) / 16, 256, 0, stream>>>(x, W1, flags, h1x, N);
    gather1_kernel<<<(N + 3) / 4, 256, 0, stream>>>(h1x, dinv, rowptr, csr_src, b1, flags, h1, N);
    gemm2_kernel<<<(N + 31) / 32, 256, 0, stream>>>(h1, W2, flags, h2x, N);
    final_kernel<<<(N + 7) / 8, 256, 0, stream>>>(x, h1, h2x, dinv, rowptr, csr_src, b2, Wl, bl, flags, d_out, N);
}

// Round 5
// 1109.446 us; speedup vs baseline: 2.5726x; 2.0986x over previous
//
#include <hip/hip_runtime.h>
#include <hip/hip_bf16.h>

typedef __hip_bfloat16 bf16;
typedef __attribute__((ext_vector_type(8))) short short8;   // 8 bf16 (4 VGPRs)
typedef __attribute__((ext_vector_type(4))) float f32x4;    // MFMA accumulator

// dual-mode float load: f32 ? float buffer : bf16 buffer (same element index)
static __device__ __forceinline__ float ldf(const void* p, long long i, bool f32) {
    return f32 ? ((const float*)p)[i] : __bfloat162float(((const bf16*)p)[i]);
}

// ---------------------------------------------------------------- encoding sniffer
// flags[0]: x is fp32?  flags[1]: weights are fp32?  flags[2]: edge_index is int64?
__global__ __launch_bounds__(256, 4)
void sniff_kernel(const void* __restrict__ x, const void* __restrict__ w,
                  const int* __restrict__ ei, int E, int* __restrict__ flags) {
    __shared__ int cnt;
    if (threadIdx.x == 0) cnt = 0;
    __syncthreads();
    if (blockIdx.x < 2) {
        const unsigned short* u = (const unsigned short*)(blockIdx.x == 0 ? x : w);
        int bad = 0;
        for (int i = threadIdx.x; i < 4096; i += 256) {
            unsigned e = (u[i] >> 7) & 0xFF;
            if (e >= 0xA0) bad++;
        }
        atomicAdd(&cnt, bad);
        __syncthreads();
        if (threadIdx.x == 0) flags[blockIdx.x] = (cnt > 16) ? 1 : 0;
    } else {
        int nz = 0;
        for (int i = threadIdx.x; i < 1024; i += 256)
            if (ei[2 * i + 1] != 0) nz++;
        atomicAdd(&cnt, nz);
        __syncthreads();
        if (threadIdx.x == 0) flags[2] = (cnt == 0) ? 1 : 0;
    }
}

static __device__ __forceinline__ int ld_src(const int* ei, int E, int e, bool i64) {
    return i64 ? ei[2 * e] : ei[e];
}
static __device__ __forceinline__ int ld_dst(const int* ei, int E, int e, bool i64) {
    return i64 ? ei[2 * (E + e)] : ei[E + e];
}

// ---------------------------------------------------------------- degree counts (int)
__global__ __launch_bounds__(256, 4)
void count_kernel(const int* __restrict__ ei, int E, const int* __restrict__ flags,
                  int* __restrict__ counts) {
    int i = blockIdx.x * blockDim.x + threadIdx.x;
    if (i >= E) return;
    bool i64 = flags[2] != 0;
    atomicAdd(&counts[ld_dst(ei, E, i, i64)], 1);
}

__global__ __launch_bounds__(256, 4)
void dinv_kernel(const int* __restrict__ counts, float* __restrict__ dinv, int N) {
    int i = blockIdx.x * blockDim.x + threadIdx.x;
    if (i < N) dinv[i] = rsqrtf((float)counts[i] + 1.0f);
}

// ---------------------------------------------------------------- exclusive scan (single block)
__global__ __launch_bounds__(256, 4)
void scan_kernel(const int* __restrict__ counts, int* __restrict__ rowptr, int N) {
    __shared__ int bs[256];
    const int T = 256;
    int chunk = (N + T - 1) / T;
    int lo = threadIdx.x * chunk;
    int hi = lo + chunk; if (hi > N) hi = N; if (lo > N) lo = N;
    int sum = 0;
    for (int i = lo; i < hi; i++) sum += counts[i];
    bs[threadIdx.x] = sum;
    __syncthreads();
    for (int off = 1; off < T; off <<= 1) {
        int t = 0;
        if ((int)threadIdx.x >= off) t = bs[threadIdx.x - off];
        __syncthreads();
        if ((int)threadIdx.x >= off) bs[threadIdx.x] += t;
        __syncthreads();
    }
    int run = bs[threadIdx.x] - sum;
    for (int i = lo; i < hi; i++) { rowptr[i] = run; run += counts[i]; }
    if (hi == N && lo < N) rowptr[N] = run;
    if (N == 0 && threadIdx.x == 0) rowptr[0] = 0;
}

// ---------------------------------------------------------------- CSR fill (counting sort by dst)
__global__ __launch_bounds__(256, 4)
void fill_kernel(const int* __restrict__ ei, int E, const int* __restrict__ flags,
                 const int* __restrict__ rowptr, int* __restrict__ cursor,
                 int* __restrict__ csr_src) {
    int e = blockIdx.x * blockDim.x + threadIdx.x;
    if (e >= E) return;
    bool i64 = flags[2] != 0;
    int s = ld_src(ei, E, e, i64), d = ld_dst(ei, E, e, i64);
    int p = atomicAdd(&cursor[d], 1);
    csr_src[rowptr[d] + p] = s;
}

// ---------------------------------------------------------------- W1 -> MFMA B-fragment pack
// Bpack slot s = (kstep*4 + ntile)*64 + lane, each 8 bf16:
//   lane L holds W1[kstep*32 + (L>>4)*8 + j][ntile*16 + (L&15)], j=0..7
__global__ __launch_bounds__(256, 4)
void repack_kernel(const void* __restrict__ W1, const int* __restrict__ flags,
                   bf16* __restrict__ Bpack) {
    bool fw = flags[1] != 0;
    for (int s = threadIdx.x; s < 1024; s += 256) {
        int kstep = s >> 8, rem = s & 255, ntile = rem >> 6, lane = rem & 63;
        int n = ntile * 16 + (lane & 15);
        int kbase = kstep * 32 + (lane >> 4) * 8;
#pragma unroll
        for (int j = 0; j < 8; j++)
            Bpack[s * 8 + j] = __float2bfloat16(ldf(W1, (long long)(kbase + j) * 64 + n, fw));
    }
}

// ---------------------------------------------------------------- GEMM1: x[N,128] @ W1[128,64] -> h1x[N,64]
// MFMA path (bf16 inputs): 1 wave -> 16x64 tile, 16 mfma_f32_16x16x32_bf16, no LDS.
// Fallback (fp32 inputs): simple 1-output/thread VALU loop.
__global__ __launch_bounds__(256, 4)
void gemm1_kernel(const void* __restrict__ x, const void* __restrict__ W1,
                  const bf16* __restrict__ Bpack, const int* __restrict__ flags,
                  float* __restrict__ h1x, int N) {
    __shared__ float Ws[128 * 64];   // only used by fallback path
    bool fx = flags[0] != 0, fw = flags[1] != 0;
    if (!fx && !fw) {
        int wave = threadIdx.x >> 6, lane = threadIdx.x & 63;
        int m0 = blockIdx.x * 64 + wave * 16;
        int m = lane & 15, quad = lane >> 4;
        int row = m0 + m;
        bool rowok = row < N;
        const short* xs = (const short*)x;
        const short8* bp = (const short8*)Bpack;
        f32x4 acc0 = {0.f,0.f,0.f,0.f}, acc1 = {0.f,0.f,0.f,0.f};
        f32x4 acc2 = {0.f,0.f,0.f,0.f}, acc3 = {0.f,0.f,0.f,0.f};
#pragma unroll
        for (int kstep = 0; kstep < 4; kstep++) {
            short8 a = {0,0,0,0,0,0,0,0};
            if (rowok) a = *(const short8*)&xs[(long long)row * 128 + kstep * 32 + quad * 8];
            short8 b0 = bp[(kstep * 4 + 0) * 64 + lane];
            short8 b1 = bp[(kstep * 4 + 1) * 64 + lane];
            short8 b2 = bp[(kstep * 4 + 2) * 64 + lane];
            short8 b3 = bp[(kstep * 4 + 3) * 64 + lane];
            acc0 = __builtin_amdgcn_mfma_f32_16x16x32_bf16(a, b0, acc0, 0, 0, 0);
            acc1 = __builtin_amdgcn_mfma_f32_16x16x32_bf16(a, b1, acc1, 0, 0, 0);
            acc2 = __builtin_amdgcn_mfma_f32_16x16x32_bf16(a, b2, acc2, 0, 0, 0);
            acc3 = __builtin_amdgcn_mfma_f32_16x16x32_bf16(a, b3, acc3, 0, 0, 0);
        }
        // C/D layout: col = lane&15, row = quad*4 + r  [verified m89/m91]
#pragma unroll
        for (int r = 0; r < 4; r++) {
            int orow = m0 + quad * 4 + r;
            if (orow < N) {
                float* o = &h1x[(long long)orow * 64];
                o[ 0 + m] = acc0[r];
                o[16 + m] = acc1[r];
                o[32 + m] = acc2[r];
                o[48 + m] = acc3[r];
            }
        }
    } else {
        for (int i = threadIdx.x; i < 128 * 64; i += 256) Ws[i] = ldf(W1, i, fw);
        __syncthreads();
        int c = threadIdx.x & 63;
        int base = blockIdx.x * 64;
        for (int rr = threadIdx.x >> 6; rr < 64; rr += 4) {
            int row = base + rr;
            if (row >= N) break;
            float acc = 0.f;
#pragma unroll 8
            for (int k = 0; k < 128; k++)
                acc = fmaf(ldf(x, (long long)row * 128 + k, fx), Ws[k * 64 + c], acc);
            h1x[(long long)row * 64 + c] = acc;
        }
    }
}

// ---------------------------------------------------------------- gather layer 1: one wave per node, lane=channel
__global__ __launch_bounds__(256, 4)
void gather1_kernel(const float* __restrict__ h1x, const float* __restrict__ dinv,
                    const int* __restrict__ rowptr, const int* __restrict__ csr_src,
                    const void* __restrict__ b1, const int* __restrict__ flags,
                    float* __restrict__ h1, int N) {
    bool fw = flags[1] != 0;
    int lane = threadIdx.x & 63;
    int node = blockIdx.x * 4 + (threadIdx.x >> 6);
    if (node >= N) return;
    int beg = rowptr[node], end = rowptr[node + 1];
    float dvd = dinv[node];
    float acc = 0.f;
    for (int b = beg; b < end; b += 64) {
        int cnt = end - b; if (cnt > 64) cnt = 64;
        int s = 0; float dvs = 0.f;
        if (lane < cnt) { s = csr_src[b + lane]; dvs = dinv[s]; }
        for (int j = 0; j < cnt; j++) {
            int sj = __shfl(s, j);
            float nm = __shfl(dvs, j) * dvd;
            acc = fmaf(h1x[(long long)sj * 64 + lane], nm, acc);
        }
    }
    float v = acc + h1x[(long long)node * 64 + lane] * (dvd * dvd) + ldf(b1, lane, fw);
    h1[(long long)node * 64 + lane] = fmaxf(v, 0.f);
}

// ---------------------------------------------------------------- GEMM2: h1[N,64] @ W2[64,32] -> h2x[N,32]
// R2-proven shape: block 256 = 8 rows x 32 cols, scalar k-loop
__global__ __launch_bounds__(256, 4)
void gemm2_kernel(const float* __restrict__ h1, const void* __restrict__ W2,
                  const int* __restrict__ flags, float* __restrict__ h2x, int N) {
    __shared__ float Ws[64 * 32];
    __shared__ float Xs[8 * 64];
    bool fw = flags[1] != 0;
    for (int i = threadIdx.x; i < 64 * 32; i += 256) Ws[i] = ldf(W2, i, fw);
    int base = blockIdx.x * 8;
    for (int i = threadIdx.x; i < 8 * 64; i += 256) {
        int r = i >> 6, k = i & 63;
        int n = base + r;
        Xs[i] = (n < N) ? h1[(long long)n * 64 + k] : 0.f;
    }
    __syncthreads();
    int ln = threadIdx.x >> 5, c = threadIdx.x & 31;
    int n = base + ln;
    if (n >= N) return;
    float acc = 0.f;
    const float* xr = &Xs[ln * 64];
#pragma unroll 8
    for (int k = 0; k < 64; k++) acc = fmaf(xr[k], Ws[k * 32 + c], acc);
    h2x[(long long)n * 32 + c] = acc;
}

// ---------------------------------------------------------------- final: fused gather2 + cat@Wl + log_softmax
// R2-proven scalar inner product
__global__ __launch_bounds__(256, 4)
void final_kernel(const void* __restrict__ x, const float* __restrict__ h1,
                  const float* __restrict__ h2x, const float* __restrict__ dinv,
                  const int* __restrict__ rowptr, const int* __restrict__ csr_src,
                  const void* __restrict__ b2, const void* __restrict__ Wl,
                  const void* __restrict__ bl, const int* __restrict__ flags,
                  void* __restrict__ out, int N) {
    __shared__ float Ws[224 * 32];
    __shared__ float Cs[8 * 224];
    bool fx = flags[0] != 0, fw = flags[1] != 0;
    for (int i = threadIdx.x; i < 224 * 32; i += 256) Ws[i] = ldf(Wl, i, fw);
    int base = blockIdx.x * 8;
    for (int i = threadIdx.x; i < 8 * 192; i += 256) {
        int r = i / 192, k = i % 192;
        int n = base + r;
        float v = 0.f;
        if (n < N) v = (k < 128) ? ldf(x, (long long)n * 128 + k, fx)
                                 : h1[(long long)n * 64 + (k - 128)];
        Cs[r * 224 + k] = v;
    }
    int g = threadIdx.x >> 5, j = threadIdx.x & 31;
    int n = base + g;
    if (n < N) {
        float dvd = dinv[n];
        int beg = rowptr[n], end = rowptr[n + 1];
        float acc = 0.f;
        for (int b = beg; b < end; b += 32) {
            int cnt = end - b; if (cnt > 32) cnt = 32;
            int s = 0; float dvs = 0.f;
            if (j < cnt) { s = csr_src[b + j]; dvs = dinv[s]; }
            for (int jj = 0; jj < cnt; jj++) {
                int sj = __shfl(s, jj, 32);
                float nm = __shfl(dvs, jj, 32) * dvd;
                acc = fmaf(h2x[(long long)sj * 32 + j], nm, acc);
            }
        }
        acc += h2x[(long long)n * 32 + j] * (dvd * dvd) + ldf(b2, j, fw);
        Cs[g * 224 + 192 + j] = acc;
    }
    __syncthreads();
    float acc = ldf(bl, j, fw);
    const float* cr = &Cs[g * 224];
#pragma unroll 8
    for (int k = 0; k < 224; k++) acc = fmaf(cr[k], Ws[k * 32 + j], acc);
    float m = acc;
    for (int o = 16; o > 0; o >>= 1) m = fmaxf(m, __shfl_xor(m, o, 32));
    float ex = __expf(acc - m);
    float s = ex;
    for (int o = 16; o > 0; o >>= 1) s += __shfl_xor(s, o, 32);
    float r = acc - m - __logf(s);
    if (n < N) {
        if (fx) ((float*)out)[(long long)n * 32 + j] = r;
        else    ((bf16*)out)[(long long)n * 32 + j] = __float2bfloat16(r);
    }
}

extern "C" void kernel_launch(void* const* d_in, const int* in_sizes, int n_in,
                              void* d_out, int out_size, void* d_ws, size_t ws_size,
                              hipStream_t stream) {
    const void* x  = d_in[0];
    const int*  ei = (const int*)d_in[1];
    const void* W1 = d_in[2];
    const void* b1 = d_in[3];
    const void* W2 = d_in[4];
    const void* b2 = d_in[5];
    const void* Wl = d_in[6];
    const void* bl = d_in[7];

    int N = in_sizes[0] / 128;
    int E = in_sizes[1] / 2;

    // ws layout (4B units):
    // [flags 16 | counts N | cursor N | dinv N | rowptr N+16 | Bpack 4096 | csr_src E | h1x N*64 | h1 N*64]
    int* ip      = (int*)d_ws;
    int* flags   = ip;
    int* counts  = ip + 16;
    int* cursor  = counts + N;
    float* dinv  = (float*)(cursor + N);
    int* rowptr  = (int*)(dinv + N);
    bf16* Bpack  = (bf16*)(rowptr + N + 16);      // 8192 bf16 = 4096 ints
    int* csr_src = (int*)Bpack + 4096;
    float* h1x   = (float*)(csr_src + E);
    float* h1    = h1x + (size_t)N * 64;
    float* h2x   = h1x;  // alias (h1x dead after gather1)

    hipMemsetAsync(ip, 0, (size_t)(16 + 2 * N) * sizeof(int), stream);

    sniff_kernel<<<3, 256, 0, stream>>>(x, W1, ei, E, flags);
    count_kernel<<<(E + 255) / 256, 256, 0, stream>>>(ei, E, flags, counts);
    dinv_kernel<<<(N + 255) / 256, 256, 0, stream>>>(counts, dinv, N);
    scan_kernel<<<1, 256, 0, stream>>>(counts, rowptr, N);
    fill_kernel<<<(E + 255) / 256, 256, 0, stream>>>(ei, E, flags, rowptr, cursor, csr_src);
    repack_kernel<<<1, 256, 0, stream>>>(W1, flags, Bpack);

    gemm1_kernel<<<(N + 63) / 64, 256, 0, stream>>>(x, W1, Bpack, flags, h1x, N);
    gather1_kernel<<<(N + 3) / 4, 256, 0, stream>>>(h1x, dinv, rowptr, csr_src, b1, flags, h1, N);
    gemm2_kernel<<<(N + 7) / 8, 256, 0, stream>>>(h1, W2, flags, h2x, N);
    final_kernel<<<(N + 7) / 8, 256, 0, stream>>>(x, h1, h2x, dinv, rowptr, csr_src, b2, Wl, bl, flags, d_out, N);
}

// Round 6
// 988.978 us; speedup vs baseline: 2.8859x; 1.1218x over previous
//
#include <hip/hip_runtime.h>
#include <hip/hip_bf16.h>

typedef __hip_bfloat16 bf16;
typedef __attribute__((ext_vector_type(8))) short short8;   // 8 bf16 (4 VGPRs)
typedef __attribute__((ext_vector_type(4))) float f32x4;    // MFMA accumulator

#define MFMA16(a, b, c) __builtin_amdgcn_mfma_f32_16x16x32_bf16((a), (b), (c), 0, 0, 0)

// dual-mode float load: f32 ? float buffer : bf16 buffer (same element index)
static __device__ __forceinline__ float ldf(const void* p, long long i, bool f32) {
    return f32 ? ((const float*)p)[i] : __bfloat162float(((const bf16*)p)[i]);
}

// ---------------------------------------------------------------- encoding sniffer
// flags[0]: x is fp32?  flags[1]: weights are fp32?  flags[2]: edge_index is int64?
__global__ __launch_bounds__(256, 4)
void sniff_kernel(const void* __restrict__ x, const void* __restrict__ w,
                  const int* __restrict__ ei, int E, int* __restrict__ flags) {
    __shared__ int cnt;
    if (threadIdx.x == 0) cnt = 0;
    __syncthreads();
    if (blockIdx.x < 2) {
        const unsigned short* u = (const unsigned short*)(blockIdx.x == 0 ? x : w);
        int bad = 0;
        for (int i = threadIdx.x; i < 4096; i += 256) {
            unsigned e = (u[i] >> 7) & 0xFF;
            if (e >= 0xA0) bad++;
        }
        atomicAdd(&cnt, bad);
        __syncthreads();
        if (threadIdx.x == 0) flags[blockIdx.x] = (cnt > 16) ? 1 : 0;
    } else {
        int nz = 0;
        for (int i = threadIdx.x; i < 1024; i += 256)
            if (ei[2 * i + 1] != 0) nz++;
        atomicAdd(&cnt, nz);
        __syncthreads();
        if (threadIdx.x == 0) flags[2] = (cnt == 0) ? 1 : 0;
    }
}

static __device__ __forceinline__ int ld_src(const int* ei, int E, int e, bool i64) {
    return i64 ? ei[2 * e] : ei[e];
}
static __device__ __forceinline__ int ld_dst(const int* ei, int E, int e, bool i64) {
    return i64 ? ei[2 * (E + e)] : ei[E + e];
}

// ---------------------------------------------------------------- degree counts (int)
__global__ __launch_bounds__(256, 4)
void count_kernel(const int* __restrict__ ei, int E, const int* __restrict__ flags,
                  int* __restrict__ counts) {
    int i = blockIdx.x * blockDim.x + threadIdx.x;
    if (i >= E) return;
    bool i64 = flags[2] != 0;
    atomicAdd(&counts[ld_dst(ei, E, i, i64)], 1);
}

__global__ __launch_bounds__(256, 4)
void dinv_kernel(const int* __restrict__ counts, float* __restrict__ dinv, int N) {
    int i = blockIdx.x * blockDim.x + threadIdx.x;
    if (i < N) dinv[i] = rsqrtf((float)counts[i] + 1.0f);
}

// ---------------------------------------------------------------- exclusive scan (single block)
__global__ __launch_bounds__(256, 4)
void scan_kernel(const int* __restrict__ counts, int* __restrict__ rowptr, int N) {
    __shared__ int bs[256];
    const int T = 256;
    int chunk = (N + T - 1) / T;
    int lo = threadIdx.x * chunk;
    int hi = lo + chunk; if (hi > N) hi = N; if (lo > N) lo = N;
    int sum = 0;
    for (int i = lo; i < hi; i++) sum += counts[i];
    bs[threadIdx.x] = sum;
    __syncthreads();
    for (int off = 1; off < T; off <<= 1) {
        int t = 0;
        if ((int)threadIdx.x >= off) t = bs[threadIdx.x - off];
        __syncthreads();
        if ((int)threadIdx.x >= off) bs[threadIdx.x] += t;
        __syncthreads();
    }
    int run = bs[threadIdx.x] - sum;
    for (int i = lo; i < hi; i++) { rowptr[i] = run; run += counts[i]; }
    if (hi == N && lo < N) rowptr[N] = run;
    if (N == 0 && threadIdx.x == 0) rowptr[0] = 0;
}

// ---------------------------------------------------------------- CSR fill (counting sort by dst)
__global__ __launch_bounds__(256, 4)
void fill_kernel(const int* __restrict__ ei, int E, const int* __restrict__ flags,
                 const int* __restrict__ rowptr, int* __restrict__ cursor,
                 int* __restrict__ csr_src) {
    int e = blockIdx.x * blockDim.x + threadIdx.x;
    if (e >= E) return;
    bool i64 = flags[2] != 0;
    int s = ld_src(ei, E, e, i64), d = ld_dst(ei, E, e, i64);
    int p = atomicAdd(&cursor[d], 1);
    csr_src[rowptr[d] + p] = s;
}

// ---------------------------------------------------------------- W1 -> MFMA B-fragment pack
// Bpack slot s = (kstep*4 + ntile)*64 + lane, each 8 bf16:
//   lane L holds W1[kstep*32 + (L>>4)*8 + j][ntile*16 + (L&15)], j=0..7
__global__ __launch_bounds__(256, 4)
void repack_kernel(const void* __restrict__ W1, const int* __restrict__ flags,
                   bf16* __restrict__ Bpack) {
    bool fw = flags[1] != 0;
    for (int s = threadIdx.x; s < 1024; s += 256) {
        int kstep = s >> 8, rem = s & 255, ntile = rem >> 6, lane = rem & 63;
        int n = ntile * 16 + (lane & 15);
        int kbase = kstep * 32 + (lane >> 4) * 8;
#pragma unroll
        for (int j = 0; j < 8; j++)
            Bpack[s * 8 + j] = __float2bfloat16(ldf(W1, (long long)(kbase + j) * 64 + n, fw));
    }
}

// ---------------------------------------------------------------- GEMM1 (MFMA, bf16 mode only)
// No LDS. 1 wave = 32 rows (2 tiles of 16x64). B-frags held in 16 regs, loaded once.
// Hot path (full blocks) has zero per-lane guards.
__global__ __launch_bounds__(256, 3)
void gemm1_mfma_kernel(const short* __restrict__ x, const bf16* __restrict__ Bpack,
                       const int* __restrict__ flags, float* __restrict__ h1x, int N) {
    if ((flags[0] | flags[1]) != 0) return;   // fp32 mode -> fallback kernel
    int lane = threadIdx.x & 63, wave = threadIdx.x >> 6;
    int m = lane & 15, quad = lane >> 4;
    int base = blockIdx.x * 128 + wave * 32;
    const short8* bp = (const short8*)Bpack;
    short8 B[16];
#pragma unroll
    for (int i = 0; i < 16; i++) B[i] = bp[i * 64 + lane];
    if (base + 32 <= N) {
#pragma unroll
        for (int t = 0; t < 2; t++) {
            int r0 = base + t * 16;
            const short* xr = &x[(long long)(r0 + m) * 128 + quad * 8];
            short8 A[4];
#pragma unroll
            for (int k = 0; k < 4; k++) A[k] = *(const short8*)(xr + k * 32);
            f32x4 acc[4];
#pragma unroll
            for (int nt = 0; nt < 4; nt++) acc[nt] = (f32x4){0.f, 0.f, 0.f, 0.f};
#pragma unroll
            for (int k = 0; k < 4; k++) {
#pragma unroll
                for (int nt = 0; nt < 4; nt++) acc[nt] = MFMA16(A[k], B[k * 4 + nt], acc[nt]);
            }
            // C/D layout: col = lane&15, row = quad*4 + r  [verified m89/m91]
            float* o = &h1x[(long long)(r0 + quad * 4) * 64 + m];
#pragma unroll
            for (int nt = 0; nt < 4; nt++) {
#pragma unroll
                for (int r = 0; r < 4; r++) o[(long long)r * 64 + nt * 16] = acc[nt][r];
            }
        }
    } else if (base < N) {
#pragma unroll
        for (int t = 0; t < 2; t++) {
            int r0 = base + t * 16;
            int row = r0 + m;
            short8 A[4];
#pragma unroll
            for (int k = 0; k < 4; k++) A[k] = (short8){0,0,0,0,0,0,0,0};
            if (row < N) {
                const short* xr = &x[(long long)row * 128 + quad * 8];
#pragma unroll
                for (int k = 0; k < 4; k++) A[k] = *(const short8*)(xr + k * 32);
            }
            f32x4 acc[4];
#pragma unroll
            for (int nt = 0; nt < 4; nt++) acc[nt] = (f32x4){0.f, 0.f, 0.f, 0.f};
#pragma unroll
            for (int k = 0; k < 4; k++) {
#pragma unroll
                for (int nt = 0; nt < 4; nt++) acc[nt] = MFMA16(A[k], B[k * 4 + nt], acc[nt]);
            }
#pragma unroll
            for (int r = 0; r < 4; r++) {
                int orow = r0 + quad * 4 + r;
                if (orow < N) {
                    float* o = &h1x[(long long)orow * 64 + m];
#pragma unroll
                    for (int nt = 0; nt < 4; nt++) o[nt * 16] = acc[nt][r];
                }
            }
        }
    }
}

// ---------------------------------------------------------------- GEMM1 fallback (fp32 mode only)
// R2-proven: 4 rows/block, Ws in LDS, scalar k-loop
__global__ __launch_bounds__(256, 4)
void gemm1_fallback_kernel(const void* __restrict__ x, const void* __restrict__ W1,
                           const int* __restrict__ flags, float* __restrict__ h1x, int N) {
    if ((flags[0] | flags[1]) == 0) return;   // bf16 mode -> MFMA kernel
    __shared__ float Ws[128 * 64];
    __shared__ float Xs[4 * 128];
    bool fx = flags[0] != 0, fw = flags[1] != 0;
    for (int i = threadIdx.x; i < 128 * 64; i += 256) Ws[i] = ldf(W1, i, fw);
    int base = blockIdx.x * 4;
    for (int i = threadIdx.x; i < 4 * 128; i += 256) {
        int r = i >> 7, k = i & 127;
        int n = base + r;
        Xs[i] = (n < N) ? ldf(x, (long long)n * 128 + k, fx) : 0.f;
    }
    __syncthreads();
    int ln = threadIdx.x >> 6, c = threadIdx.x & 63;
    int n = base + ln;
    if (n >= N) return;
    float acc = 0.f;
    const float* xr = &Xs[ln * 128];
#pragma unroll 8
    for (int k = 0; k < 128; k++) acc = fmaf(xr[k], Ws[k * 64 + c], acc);
    h1x[(long long)n * 64 + c] = acc;
}

// ---------------------------------------------------------------- gather layer 1: one wave per node, lane=channel
__global__ __launch_bounds__(256, 4)
void gather1_kernel(const float* __restrict__ h1x, const float* __restrict__ dinv,
                    const int* __restrict__ rowptr, const int* __restrict__ csr_src,
                    const void* __restrict__ b1, const int* __restrict__ flags,
                    float* __restrict__ h1, int N) {
    bool fw = flags[1] != 0;
    int lane = threadIdx.x & 63;
    int node = blockIdx.x * 4 + (threadIdx.x >> 6);
    if (node >= N) return;
    int beg = rowptr[node], end = rowptr[node + 1];
    float dvd = dinv[node];
    float acc = 0.f;
    for (int b = beg; b < end; b += 64) {
        int cnt = end - b; if (cnt > 64) cnt = 64;
        int s = 0; float dvs = 0.f;
        if (lane < cnt) { s = csr_src[b + lane]; dvs = dinv[s]; }
        for (int j = 0; j < cnt; j++) {
            int sj = __shfl(s, j);
            float nm = __shfl(dvs, j) * dvd;
            acc = fmaf(h1x[(long long)sj * 64 + lane], nm, acc);
        }
    }
    float v = acc + h1x[(long long)node * 64 + lane] * (dvd * dvd) + ldf(b1, lane, fw);
    h1[(long long)node * 64 + lane] = fmaxf(v, 0.f);
}

// ---------------------------------------------------------------- GEMM2: h1[N,64] @ W2[64,32] -> h2x[N,32]
__global__ __launch_bounds__(256, 4)
void gemm2_kernel(const float* __restrict__ h1, const void* __restrict__ W2,
                  const int* __restrict__ flags, float* __restrict__ h2x, int N) {
    __shared__ float Ws[64 * 32];
    __shared__ float Xs[8 * 64];
    bool fw = flags[1] != 0;
    for (int i = threadIdx.x; i < 64 * 32; i += 256) Ws[i] = ldf(W2, i, fw);
    int base = blockIdx.x * 8;
    for (int i = threadIdx.x; i < 8 * 64; i += 256) {
        int r = i >> 6, k = i & 63;
        int n = base + r;
        Xs[i] = (n < N) ? h1[(long long)n * 64 + k] : 0.f;
    }
    __syncthreads();
    int ln = threadIdx.x >> 5, c = threadIdx.x & 31;
    int n = base + ln;
    if (n >= N) return;
    float acc = 0.f;
    const float* xr = &Xs[ln * 64];
#pragma unroll 8
    for (int k = 0; k < 64; k++) acc = fmaf(xr[k], Ws[k * 32 + c], acc);
    h2x[(long long)n * 32 + c] = acc;
}

// ---------------------------------------------------------------- final: fused gather2 + cat@Wl + log_softmax
__global__ __launch_bounds__(256, 4)
void final_kernel(const void* __restrict__ x, const float* __restrict__ h1,
                  const float* __restrict__ h2x, const float* __restrict__ dinv,
                  const int* __restrict__ rowptr, const int* __restrict__ csr_src,
                  const void* __restrict__ b2, const void* __restrict__ Wl,
                  const void* __restrict__ bl, const int* __restrict__ flags,
                  void* __restrict__ out, int N) {
    __shared__ float Ws[224 * 32];
    __shared__ float Cs[8 * 224];
    bool fx = flags[0] != 0, fw = flags[1] != 0;
    for (int i = threadIdx.x; i < 224 * 32; i += 256) Ws[i] = ldf(Wl, i, fw);
    int base = blockIdx.x * 8;
    for (int i = threadIdx.x; i < 8 * 192; i += 256) {
        int r = i / 192, k = i % 192;
        int n = base + r;
        float v = 0.f;
        if (n < N) v = (k < 128) ? ldf(x, (long long)n * 128 + k, fx)
                                 : h1[(long long)n * 64 + (k - 128)];
        Cs[r * 224 + k] = v;
    }
    int g = threadIdx.x >> 5, j = threadIdx.x & 31;
    int n = base + g;
    if (n < N) {
        float dvd = dinv[n];
        int beg = rowptr[n], end = rowptr[n + 1];
        float acc = 0.f;
        for (int b = beg; b < end; b += 32) {
            int cnt = end - b; if (cnt > 32) cnt = 32;
            int s = 0; float dvs = 0.f;
            if (j < cnt) { s = csr_src[b + j]; dvs = dinv[s]; }
            for (int jj = 0; jj < cnt; jj++) {
                int sj = __shfl(s, jj, 32);
                float nm = __shfl(dvs, jj, 32) * dvd;
                acc = fmaf(h2x[(long long)sj * 32 + j], nm, acc);
            }
        }
        acc += h2x[(long long)n * 32 + j] * (dvd * dvd) + ldf(b2, j, fw);
        Cs[g * 224 + 192 + j] = acc;
    }
    __syncthreads();
    float acc = ldf(bl, j, fw);
    const float* cr = &Cs[g * 224];
#pragma unroll 8
    for (int k = 0; k < 224; k++) acc = fmaf(cr[k], Ws[k * 32 + j], acc);
    float m = acc;
    for (int o = 16; o > 0; o >>= 1) m = fmaxf(m, __shfl_xor(m, o, 32));
    float ex = __expf(acc - m);
    float s = ex;
    for (int o = 16; o > 0; o >>= 1) s += __shfl_xor(s, o, 32);
    float r = acc - m - __logf(s);
    if (n < N) {
        if (fx) ((float*)out)[(long long)n * 32 + j] = r;
        else    ((bf16*)out)[(long long)n * 32 + j] = __float2bfloat16(r);
    }
}

extern "C" void kernel_launch(void* const* d_in, const int* in_sizes, int n_in,
                              void* d_out, int out_size, void* d_ws, size_t ws_size,
                              hipStream_t stream) {
    const void* x  = d_in[0];
    const int*  ei = (const int*)d_in[1];
    const void* W1 = d_in[2];
    const void* b1 = d_in[3];
    const void* W2 = d_in[4];
    const void* b2 = d_in[5];
    const void* Wl = d_in[6];
    const void* bl = d_in[7];

    int N = in_sizes[0] / 128;
    int E = in_sizes[1] / 2;

    // ws layout (4B units):
    // [flags 16 | counts N | cursor N | dinv N | rowptr N+16 | Bpack 4096 | csr_src E | h1x N*64 | h1 N*64]
    int* ip      = (int*)d_ws;
    int* flags   = ip;
    int* counts  = ip + 16;
    int* cursor  = counts + N;
    float* dinv  = (float*)(cursor + N);
    int* rowptr  = (int*)(dinv + N);
    bf16* Bpack  = (bf16*)(rowptr + N + 16);      // 8192 bf16 = 4096 ints
    int* csr_src = (int*)Bpack + 4096;
    float* h1x   = (float*)(csr_src + E);
    float* h1    = h1x + (size_t)N * 64;
    float* h2x   = h1x;  // alias (h1x dead after gather1)

    hipMemsetAsync(ip, 0, (size_t)(16 + 2 * N) * sizeof(int), stream);

    sniff_kernel<<<3, 256, 0, stream>>>(x, W1, ei, E, flags);
    count_kernel<<<(E + 255) / 256, 256, 0, stream>>>(ei, E, flags, counts);
    dinv_kernel<<<(N + 255) / 256, 256, 0, stream>>>(counts, dinv, N);
    scan_kernel<<<1, 256, 0, stream>>>(counts, rowptr, N);
    fill_kernel<<<(E + 255) / 256, 256, 0, stream>>>(ei, E, flags, rowptr, cursor, csr_src);
    repack_kernel<<<1, 256, 0, stream>>>(W1, flags, Bpack);

    gemm1_mfma_kernel<<<(N + 127) / 128, 256, 0, stream>>>((const short*)x, Bpack, flags, h1x, N);
    gemm1_fallback_kernel<<<(N + 3) / 4, 256, 0, stream>>>(x, W1, flags, h1x, N);
    gather1_kernel<<<(N + 3) / 4, 256, 0, stream>>>(h1x, dinv, rowptr, csr_src, b1, flags, h1, N);
    gemm2_kernel<<<(N + 7) / 8, 256, 0, stream>>>(h1, W2, flags, h2x, N);
    final_kernel<<<(N + 7) / 8, 256, 0, stream>>>(x, h1, h2x, dinv, rowptr, csr_src, b2, Wl, bl, flags, d_out, N);
}